// Round 7
// baseline (84.939 us; speedup 1.0000x reference)
//
#include <hip/hip_runtime.h>
#include <hip/hip_bf16.h>

#define MIN_PTS 4

typedef short bf16x8 __attribute__((ext_vector_type(8)));
typedef float f32x4  __attribute__((ext_vector_type(4)));

__device__ __forceinline__ ushort f2bf(float x) {
    unsigned u = __float_as_uint(x);
    u = (u + 0x7fffu + ((u >> 16) & 1u)) >> 16;   // RNE, finite inputs
    return (ushort)u;
}

// v_cvt_pk_bf16_f32: lo -> low 16, hi -> high 16 (RNE)
__device__ __forceinline__ uint cvt_pk_bf16(float lo, float hi) {
    union { __hip_bfloat162 h; uint u; } cv;
    cv.h = __float22bfloat162_rn(make_float2(lo, hi));
    return cv.u;
}

// Pack W2 [64][128] and W3 [128][256] (fp32 row-major, K x N) into bf16
// MFMA B-fragment-linear layout: [ntile][kstep][lane][8], where
// element j of lane l = W[k = 32*ks + 8*(l>>4) + j][col = 16*nt + (l&15)].
__global__ void pack_weights(const float* __restrict__ W2, const float* __restrict__ W3,
                             ushort* __restrict__ B2P, ushort* __restrict__ B3P)
{
    int idx = blockIdx.x * 256 + threadIdx.x;
    if (idx < 8192) {   // W2: 8 ntiles x 2 ksteps x 64 lanes x 8
        int j = idx & 7, l = (idx >> 3) & 63, ks = (idx >> 9) & 1, nt = idx >> 10;
        int k   = ks * 32 + (l >> 4) * 8 + j;
        int col = nt * 16 + (l & 15);
        B2P[idx] = f2bf(W2[k * 128 + col]);
    }
    if (idx < 32768) {  // W3: 16 ntiles x 4 ksteps x 64 lanes x 8
        int j = idx & 7, l = (idx >> 3) & 63, ks = (idx >> 9) & 3, nt = idx >> 11;
        int k   = ks * 32 + (l >> 4) * 8 + j;
        int col = nt * 16 + (l & 15);
        B3P[idx] = f2bf(W3[k * 256 + col]);
    }
}

// One block (4 waves, 256 thr) = one 32-point stripe of one proposal.
// Wave w: layer1 feats 16w..16w+15 (split by lane-half h); layer2 ntiles
// {2w,2w+1}; layer3 ntiles {4w..4w+3}.
__global__ __launch_bounds__(256, 8) void refine_stripe32(
    const float* __restrict__ points,    // [P][N][3]
    const int*   __restrict__ lengths,   // [P]
    const float* __restrict__ proposals, // [P][6]
    const float* __restrict__ W1, const float* __restrict__ b1,   // [3][64],[64]
    const float* __restrict__ b2,                                  // [128]
    const float* __restrict__ b3,                                  // [256]
    const ushort* __restrict__ B2P, const ushort* __restrict__ B3P,
    int* __restrict__ featsG,            // [P][256] f32 bits, pre-zeroed
    int P, int N)
{
    const int bid = blockIdx.x;
    const int p   = bid >> 3;
    const int s   = bid & 7;
    const int len = lengths[p];
    if (len < MIN_PTS || s * 32 >= len) return;   // feats stay 0 -> bias-only heads

    __shared__ __align__(16) ushort A1[2048];   // h1 frags [mt(2)][ks(2)][lane][8] = 4 KB
    __shared__ __align__(16) ushort A3[4096];   // h2 frags [mt(2)][ks(4)][lane][8] = 8 KB

    const int tid  = threadIdx.x;
    const int lane = tid & 63;
    const int wu   = __builtin_amdgcn_readfirstlane(tid >> 6);  // wave id 0..3
    const int rc   = lane & 15;
    const int g    = lane >> 4;          // 0..3
    const int h    = lane >> 5;          // 0..1
    const int ptl  = lane & 31;          // point within stripe
    const int mtA  = (lane >> 4) & 1;    // ptl >> 4

    // proposal params (block-uniform -> scalar)
    const float cx = proposals[p * 6 + 0];
    const float cy = proposals[p * 6 + 1];
    const float cz = proposals[p * 6 + 2];
    const float rx = __builtin_amdgcn_rcpf(fmaf(proposals[p * 6 + 3], 0.5f, 1e-6f));
    const float ry = __builtin_amdgcn_rcpf(fmaf(proposals[p * 6 + 4], 0.5f, 1e-6f));
    const float rz = __builtin_amdgcn_rcpf(fmaf(proposals[p * 6 + 5], 0.5f, 1e-6f));

    // ---------- Phase A: layer 1 (3->64); each lane does 8 feats of its point ----------
    {
        const int jj = min(s * 32 + ptl, len - 1);     // duplicate last point (max-safe)
        const float* pt = points + ((long)p * N + jj) * 3;
        const float x0 = (pt[0] - cx) * rx;
        const float x1 = (pt[1] - cy) * ry;
        const float x2 = (pt[2] - cz) * rz;

        const int f0 = 16 * wu + 8 * h;                // this lane's 8 consecutive feats
        const float4 wa0 = *(const float4*)&W1[f0],       wa1 = *(const float4*)&W1[f0 + 4];
        const float4 wb0 = *(const float4*)&W1[64 + f0],  wb1 = *(const float4*)&W1[64 + f0 + 4];
        const float4 wc0 = *(const float4*)&W1[128 + f0], wc1 = *(const float4*)&W1[128 + f0 + 4];
        const float4 bb0 = *(const float4*)&b1[f0],       bb1 = *(const float4*)&b1[f0 + 4];

        float v[8];
        v[0] = fmaxf(fmaf(x0, wa0.x, fmaf(x1, wb0.x, fmaf(x2, wc0.x, bb0.x))), 0.f);
        v[1] = fmaxf(fmaf(x0, wa0.y, fmaf(x1, wb0.y, fmaf(x2, wc0.y, bb0.y))), 0.f);
        v[2] = fmaxf(fmaf(x0, wa0.z, fmaf(x1, wb0.z, fmaf(x2, wc0.z, bb0.z))), 0.f);
        v[3] = fmaxf(fmaf(x0, wa0.w, fmaf(x1, wb0.w, fmaf(x2, wc0.w, bb0.w))), 0.f);
        v[4] = fmaxf(fmaf(x0, wa1.x, fmaf(x1, wb1.x, fmaf(x2, wc1.x, bb1.x))), 0.f);
        v[5] = fmaxf(fmaf(x0, wa1.y, fmaf(x1, wb1.y, fmaf(x2, wc1.y, bb1.y))), 0.f);
        v[6] = fmaxf(fmaf(x0, wa1.z, fmaf(x1, wb1.z, fmaf(x2, wc1.z, bb1.z))), 0.f);
        v[7] = fmaxf(fmaf(x0, wa1.w, fmaf(x1, wb1.w, fmaf(x2, wc1.w, bb1.w))), 0.f);

        uint4 qq;
        qq.x = cvt_pk_bf16(v[0], v[1]);
        qq.y = cvt_pk_bf16(v[2], v[3]);
        qq.z = cvt_pk_bf16(v[4], v[5]);
        qq.w = cvt_pk_bf16(v[6], v[7]);
        // A1 slot: k0 = 16w+8h -> ks = w>>1, lane-group g2 = (2w+h)&3
        const int chunk = (mtA * 2 + (wu >> 1)) * 64 + ((2 * wu + h) & 3) * 16 + rc;
        *(uint4*)&A1[chunk * 8] = qq;
    }
    __syncthreads();

    // ---------- Phase B: layer 2 (64->128), swapped operands, ntiles {2w,2w+1} ----------
    {
        f32x4 acc2[2][2];   // [mt][nt]
        #pragma unroll
        for (int nt = 0; nt < 2; ++nt) {
            f32x4 bq;
            #pragma unroll
            for (int rr = 0; rr < 4; ++rr) bq[rr] = b2[32 * wu + 16 * nt + 4 * g + rr];
            acc2[0][nt] = bq; acc2[1][nt] = bq;        // bias folded
        }
        #pragma unroll
        for (int ks = 0; ks < 2; ++ks) {
            const bf16x8 bw0 = *(const bf16x8*)(B2P + (((2 * wu + 0) * 2 + ks) * 64 + lane) * 8);
            const bf16x8 bw1 = *(const bf16x8*)(B2P + (((2 * wu + 1) * 2 + ks) * 64 + lane) * 8);
            #pragma unroll
            for (int mt = 0; mt < 2; ++mt) {
                const bf16x8 a = *(const bf16x8*)&A1[((mt * 2 + ks) * 64 + lane) * 8];
                acc2[mt][0] = __builtin_amdgcn_mfma_f32_16x16x32_bf16(bw0, a, acc2[mt][0], 0, 0, 0);
                acc2[mt][1] = __builtin_amdgcn_mfma_f32_16x16x32_bf16(bw1, a, acc2[mt][1], 0, 0, 0);
            }
        }
        // relu + pack: feat k0 = 32w+16nt+4g -> ks3 = w, g3 = (2nt+(g>>1))&3
        #pragma unroll
        for (int mt = 0; mt < 2; ++mt)
            #pragma unroll
            for (int nt = 0; nt < 2; ++nt) {
                const uint u0 = cvt_pk_bf16(fmaxf(acc2[mt][nt][0], 0.f), fmaxf(acc2[mt][nt][1], 0.f));
                const uint u1 = cvt_pk_bf16(fmaxf(acc2[mt][nt][2], 0.f), fmaxf(acc2[mt][nt][3], 0.f));
                const int g3 = (2 * nt + (g >> 1)) & 3;
                const int chunk = (mt * 4 + wu) * 64 + g3 * 16 + rc;
                uint2 val; val.x = u0; val.y = u1;
                *(uint2*)&A3[chunk * 8 + (g & 1) * 4] = val;
            }
    }
    __syncthreads();

    // ---------- Phase D: layer 3 (128->256), ntiles {4w..4w+3} in 2 halves, fused pool ----------
    #pragma unroll 1
    for (int nh = 0; nh < 2; ++nh) {
        const int nt0 = 4 * wu + 2 * nh, nt1 = nt0 + 1;
        const float b30 = b3[16 * nt0 + rc];
        const float b31 = b3[16 * nt1 + rc];
        f32x4 acc[2][2];   // [mt][j]
        #pragma unroll
        for (int mt = 0; mt < 2; ++mt) {
            acc[mt][0] = (f32x4){b30, b30, b30, b30};   // bias folded
            acc[mt][1] = (f32x4){b31, b31, b31, b31};
        }
        #pragma unroll
        for (int ks = 0; ks < 4; ++ks) {
            const bf16x8 bf0 = *(const bf16x8*)(B3P + ((nt0 * 4 + ks) * 64 + lane) * 8);
            const bf16x8 bf1 = *(const bf16x8*)(B3P + ((nt1 * 4 + ks) * 64 + lane) * 8);
            #pragma unroll
            for (int mt = 0; mt < 2; ++mt) {
                const bf16x8 a = *(const bf16x8*)&A3[((mt * 4 + ks) * 64 + lane) * 8];
                acc[mt][0] = __builtin_amdgcn_mfma_f32_16x16x32_bf16(a, bf0, acc[mt][0], 0, 0, 0);
                acc[mt][1] = __builtin_amdgcn_mfma_f32_16x16x32_bf16(a, bf1, acc[mt][1], 0, 0, 0);
            }
        }
        float pool0 = 0.f, pool1 = 0.f;   // relu folded into 0-init
        #pragma unroll
        for (int mt = 0; mt < 2; ++mt)
            #pragma unroll
            for (int rr = 0; rr < 4; ++rr) {
                pool0 = fmaxf(pool0, acc[mt][0][rr]);
                pool1 = fmaxf(pool1, acc[mt][1][rr]);
            }
        pool0 = fmaxf(pool0, __shfl_xor(pool0, 16, 64));
        pool0 = fmaxf(pool0, __shfl_xor(pool0, 32, 64));
        pool1 = fmaxf(pool1, __shfl_xor(pool1, 16, 64));
        pool1 = fmaxf(pool1, __shfl_xor(pool1, 32, 64));
        if (g == 0) {
            atomicMax(&featsG[p * 256 + nt0 * 16 + rc], __float_as_int(pool0));
            atomicMax(&featsG[p * 256 + nt1 * 16 + rc], __float_as_int(pool1));
        }
    }
}

// One wave per proposal: 5 dot products of length 256.
__global__ __launch_bounds__(256) void heads_kernel(
    const int* __restrict__ featsG,
    const float* __restrict__ Wc, const float* __restrict__ bc,
    const float* __restrict__ Wr, const float* __restrict__ br,
    float* __restrict__ out, int P)
{
    const int tid  = threadIdx.x;
    const int lane = tid & 63;
    const int p    = blockIdx.x * 4 + (tid >> 6);
    if (p >= P) return;

    const int4 vi = *(const int4*)&featsG[p * 256 + lane * 4];
    float v[4] = {__int_as_float(vi.x), __int_as_float(vi.y),
                  __int_as_float(vi.z), __int_as_float(vi.w)};

    const float4 wc = *(const float4*)&Wc[lane * 4];
    float c  = v[0] * wc.x + v[1] * wc.y + v[2] * wc.z + v[3] * wc.w;
    float r0 = 0.f, r1 = 0.f, r2 = 0.f, r3 = 0.f;
    #pragma unroll
    for (int i = 0; i < 4; ++i) {
        const float4 wr = *(const float4*)&Wr[(lane * 4 + i) * 4];
        r0 = fmaf(v[i], wr.x, r0);
        r1 = fmaf(v[i], wr.y, r1);
        r2 = fmaf(v[i], wr.z, r2);
        r3 = fmaf(v[i], wr.w, r3);
    }
    #pragma unroll
    for (int off = 32; off > 0; off >>= 1) {
        c  += __shfl_xor(c,  off, 64);
        r0 += __shfl_xor(r0, off, 64);
        r1 += __shfl_xor(r1, off, 64);
        r2 += __shfl_xor(r2, off, 64);
        r3 += __shfl_xor(r3, off, 64);
    }
    if (lane == 0) {
        out[p]             = c  + bc[0];
        out[P + p * 4 + 0] = r0 + br[0];
        out[P + p * 4 + 1] = r1 + br[1];
        out[P + p * 4 + 2] = r2 + br[2];
        out[P + p * 4 + 3] = r3 + br[3];
    }
}

extern "C" void kernel_launch(void* const* d_in, const int* in_sizes, int n_in,
                              void* d_out, int out_size, void* d_ws, size_t ws_size,
                              hipStream_t stream)
{
    const float* points    = (const float*)d_in[0];
    const int*   lengths   = (const int*)  d_in[1];
    const float* proposals = (const float*)d_in[2];
    const float* W1 = (const float*)d_in[3];
    const float* b1 = (const float*)d_in[4];
    const float* W2 = (const float*)d_in[5];
    const float* b2 = (const float*)d_in[6];
    const float* W3 = (const float*)d_in[7];
    const float* b3 = (const float*)d_in[8];
    const float* Wc = (const float*)d_in[9];
    const float* bc = (const float*)d_in[10];
    const float* Wr = (const float*)d_in[11];
    const float* br = (const float*)d_in[12];
    float* out = (float*)d_out;

    const int P = in_sizes[1];              // 2048
    const int N = in_sizes[0] / (3 * P);    // 256
    const int S32 = (N + 31) / 32;          // 8 stripes of 32 points

    ushort* B2P    = (ushort*)d_ws;                 // 8192 bf16  (16 KB)
    ushort* B3P    = B2P + 8192;                    // 32768 bf16 (64 KB)
    int*    featsG = (int*)((char*)d_ws + 81920);   // P*256 ints (2 MB)

    hipMemsetAsync(featsG, 0, (size_t)P * 256 * sizeof(int), stream);
    pack_weights<<<dim3(128), dim3(256), 0, stream>>>(W2, W3, B2P, B3P);
    refine_stripe32<<<dim3(P * S32), dim3(256), 0, stream>>>(
        points, lengths, proposals, W1, b1, b2, b3, B2P, B3P, featsG, P, N);
    heads_kernel<<<dim3((P + 3) / 4), dim3(256), 0, stream>>>(
        featsG, Wc, bc, Wr, br, out, P);
}

// Round 8
// 55.043 us; speedup vs baseline: 1.5431x; 1.5431x over previous
//
#include <hip/hip_runtime.h>
#include <hip/hip_bf16.h>

#define MIN_PTS 4

typedef short bf16x8 __attribute__((ext_vector_type(8)));
typedef float f32x4  __attribute__((ext_vector_type(4)));

__device__ __forceinline__ ushort f2bf(float x) {
    unsigned u = __float_as_uint(x);
    u = (u + 0x7fffu + ((u >> 16) & 1u)) >> 16;   // RNE, finite inputs
    return (ushort)u;
}

// v_cvt_pk_bf16_f32: lo -> low 16, hi -> high 16 (RNE)
__device__ __forceinline__ uint cvt_pk_bf16(float lo, float hi) {
    union { __hip_bfloat162 h; uint u; } cv;
    cv.h = __float22bfloat162_rn(make_float2(lo, hi));
    return cv.u;
}

// Pack W2 [64][128] and W3 [128][256] (fp32 row-major, K x N) into bf16
// MFMA B-fragment-linear layout: [ntile][kstep][lane][8], where
// element j of lane l = W[k = 32*ks + 8*(l>>4) + j][col = 16*nt + (l&15)].
__global__ void pack_weights(const float* __restrict__ W2, const float* __restrict__ W3,
                             ushort* __restrict__ B2P, ushort* __restrict__ B3P)
{
    int idx = blockIdx.x * 256 + threadIdx.x;
    if (idx < 8192) {   // W2: 8 ntiles x 2 ksteps x 64 lanes x 8
        int j = idx & 7, l = (idx >> 3) & 63, ks = (idx >> 9) & 1, nt = idx >> 10;
        int k   = ks * 32 + (l >> 4) * 8 + j;
        int col = nt * 16 + (l & 15);
        B2P[idx] = f2bf(W2[k * 128 + col]);
    }
    if (idx < 32768) {  // W3: 16 ntiles x 4 ksteps x 64 lanes x 8
        int j = idx & 7, l = (idx >> 3) & 63, ks = (idx >> 9) & 3, nt = idx >> 11;
        int k   = ks * 32 + (l >> 4) * 8 + j;
        int col = nt * 16 + (l & 15);
        B3P[idx] = f2bf(W3[k * 256 + col]);
    }
}

// One block (8 waves, 512 thr) = one 128-point stripe of one proposal.
// Phase A: wave-pair wp=w>>1 computes feats 16wp..16wp+15; thread owns point
//          (w&1)*64+lane.
// Phase B (layer2, swapped): wave = mtiles {4(w>>2)..+3} x ntiles {2(w&3),+1}.
// Phase D (layer3): wave = mtiles {4(w>>2)..+3} x ntiles {4(w&3)..+3}.
__global__ __launch_bounds__(512, 4) void refine_stripe128(
    const float* __restrict__ points,    // [P][N][3]
    const int*   __restrict__ lengths,   // [P]
    const float* __restrict__ proposals, // [P][6]
    const float* __restrict__ W1, const float* __restrict__ b1,   // [3][64],[64]
    const float* __restrict__ b2,                                  // [128]
    const float* __restrict__ b3,                                  // [256]
    const ushort* __restrict__ B2P, const ushort* __restrict__ B3P,
    int* __restrict__ featsG,            // [P][256] f32 bits, pre-zeroed
    int P, int N)
{
    const int bid = blockIdx.x;
    const int p   = bid >> 1;
    const int s   = bid & 1;
    const int len = lengths[p];
    if (len < MIN_PTS || s * 128 >= len) return;   // feats stay 0 -> bias-only heads

    __shared__ __align__(16) ushort A1[8192];    // [mt(8)][ks(2)][lane][8] = 16 KB
    __shared__ __align__(16) ushort A3[16384];   // [mt(8)][ks(4)][lane][8] = 32 KB

    const int tid  = threadIdx.x;
    const int lane = tid & 63;
    const int wu   = __builtin_amdgcn_readfirstlane(tid >> 6);  // wave id 0..7
    const int rc   = lane & 15;
    const int g    = lane >> 4;          // 0..3
    const int mtg  = wu >> 2;            // 0..1  (mtile group)
    const int ntg  = wu & 3;             // 0..3  (ntile group)

    // proposal params (block-uniform -> scalar)
    const float cx = proposals[p * 6 + 0];
    const float cy = proposals[p * 6 + 1];
    const float cz = proposals[p * 6 + 2];
    const float rx = __builtin_amdgcn_rcpf(fmaf(proposals[p * 6 + 3], 0.5f, 1e-6f));
    const float ry = __builtin_amdgcn_rcpf(fmaf(proposals[p * 6 + 4], 0.5f, 1e-6f));
    const float rz = __builtin_amdgcn_rcpf(fmaf(proposals[p * 6 + 5], 0.5f, 1e-6f));

    // ---------- Phase A: layer 1 (3->64) ----------
    // wave-pair wp computes feats 16wp..16wp+15 for all 128 points;
    // this thread's point: pis = (w&1)*64 + lane.
    {
        const int wp  = wu >> 1;                       // wave-uniform
        const int pis = (wu & 1) * 64 + lane;          // point in stripe
        const int jj  = min(s * 128 + pis, len - 1);   // duplicate last point (max-safe)
        const float* pt = points + ((long)p * N + jj) * 3;
        const float x0 = (pt[0] - cx) * rx;
        const float x1 = (pt[1] - cy) * ry;
        const float x2 = (pt[2] - cz) * rz;

        float v[16];
        #pragma unroll
        for (int i = 0; i < 16; ++i) {
            const int f = 16 * wp + i;                 // wave-uniform -> scalar loads
            v[i] = fmaxf(fmaf(x0, W1[f], fmaf(x1, W1[64 + f], fmaf(x2, W1[128 + f], b1[f]))), 0.f);
        }
        const int mt = pis >> 4;                       // 0..7
        #pragma unroll
        for (int c = 0; c < 2; ++c) {
            uint4 qq;
            qq.x = cvt_pk_bf16(v[8 * c + 0], v[8 * c + 1]);
            qq.y = cvt_pk_bf16(v[8 * c + 2], v[8 * c + 3]);
            qq.z = cvt_pk_bf16(v[8 * c + 4], v[8 * c + 5]);
            qq.w = cvt_pk_bf16(v[8 * c + 6], v[8 * c + 7]);
            // k0 = 16wp + 8c -> ks = wp>>1, lane-group g2 = (2wp+c)&3
            const int chunk = (mt * 2 + (wp >> 1)) * 64 + ((2 * wp + c) & 3) * 16 + rc;
            *(uint4*)&A1[chunk * 8] = qq;
        }
    }
    __syncthreads();

    // ---------- Phase B: layer 2 (64->128), swapped operands ----------
    // wave tile: mtiles {4mtg..+3} x ntiles {2ntg, 2ntg+1}
    {
        f32x4 acc2[4][2];
        #pragma unroll
        for (int nt = 0; nt < 2; ++nt) {
            f32x4 bq;
            #pragma unroll
            for (int rr = 0; rr < 4; ++rr) bq[rr] = b2[16 * (2 * ntg + nt) + 4 * g + rr];
            #pragma unroll
            for (int mt = 0; mt < 4; ++mt) acc2[mt][nt] = bq;   // bias folded
        }
        #pragma unroll
        for (int ks = 0; ks < 2; ++ks) {
            const bf16x8 bw0 = *(const bf16x8*)(B2P + (((2 * ntg + 0) * 2 + ks) * 64 + lane) * 8);
            const bf16x8 bw1 = *(const bf16x8*)(B2P + (((2 * ntg + 1) * 2 + ks) * 64 + lane) * 8);
            #pragma unroll
            for (int mt = 0; mt < 4; ++mt) {
                const bf16x8 a = *(const bf16x8*)&A1[(((4 * mtg + mt) * 2 + ks) * 64 + lane) * 8];
                acc2[mt][0] = __builtin_amdgcn_mfma_f32_16x16x32_bf16(bw0, a, acc2[mt][0], 0, 0, 0);
                acc2[mt][1] = __builtin_amdgcn_mfma_f32_16x16x32_bf16(bw1, a, acc2[mt][1], 0, 0, 0);
            }
        }
        // relu + pack 4 consecutive layer-3 k's of one point -> ds_write_b64
        // k0 = 16(2ntg+nt)+4g -> ks3 = ntg, g3 = (2nt+(g>>1))&3, off (g&1)*4
        #pragma unroll
        for (int mt = 0; mt < 4; ++mt)
            #pragma unroll
            for (int nt = 0; nt < 2; ++nt) {
                const uint u0 = cvt_pk_bf16(fmaxf(acc2[mt][nt][0], 0.f), fmaxf(acc2[mt][nt][1], 0.f));
                const uint u1 = cvt_pk_bf16(fmaxf(acc2[mt][nt][2], 0.f), fmaxf(acc2[mt][nt][3], 0.f));
                const int g3 = (2 * nt + (g >> 1)) & 3;
                const int chunk = ((4 * mtg + mt) * 4 + ntg) * 64 + g3 * 16 + rc;
                uint2 val; val.x = u0; val.y = u1;
                *(uint2*)&A3[chunk * 8 + (g & 1) * 4] = val;
            }
    }
    __syncthreads();

    // ---------- Phase D: layer 3 (128->256), wave = 4mt x 4nt, fused pool ----------
    {
        f32x4 acc3[4][4];   // [mt][nt] -- 64 VGPR
        #pragma unroll
        for (int nt = 0; nt < 4; ++nt) {
            const float bv = b3[16 * (4 * ntg + nt) + rc];
            #pragma unroll
            for (int mt = 0; mt < 4; ++mt)
                acc3[mt][nt] = (f32x4){bv, bv, bv, bv};         // bias folded
        }
        #pragma unroll
        for (int ks = 0; ks < 4; ++ks) {
            const bf16x8 b0 = *(const bf16x8*)(B3P + (((4 * ntg + 0) * 4 + ks) * 64 + lane) * 8);
            const bf16x8 b1f = *(const bf16x8*)(B3P + (((4 * ntg + 1) * 4 + ks) * 64 + lane) * 8);
            const bf16x8 b2f = *(const bf16x8*)(B3P + (((4 * ntg + 2) * 4 + ks) * 64 + lane) * 8);
            const bf16x8 b3f = *(const bf16x8*)(B3P + (((4 * ntg + 3) * 4 + ks) * 64 + lane) * 8);
            #pragma unroll
            for (int mt = 0; mt < 4; ++mt) {
                const bf16x8 a = *(const bf16x8*)&A3[(((4 * mtg + mt) * 4 + ks) * 64 + lane) * 8];
                acc3[mt][0] = __builtin_amdgcn_mfma_f32_16x16x32_bf16(a, b0,  acc3[mt][0], 0, 0, 0);
                acc3[mt][1] = __builtin_amdgcn_mfma_f32_16x16x32_bf16(a, b1f, acc3[mt][1], 0, 0, 0);
                acc3[mt][2] = __builtin_amdgcn_mfma_f32_16x16x32_bf16(a, b2f, acc3[mt][2], 0, 0, 0);
                acc3[mt][3] = __builtin_amdgcn_mfma_f32_16x16x32_bf16(a, b3f, acc3[mt][3], 0, 0, 0);
            }
        }
        float pool[4];
        #pragma unroll
        for (int nt = 0; nt < 4; ++nt) {
            float m = 0.f;   // relu folded
            #pragma unroll
            for (int mt = 0; mt < 4; ++mt)
                #pragma unroll
                for (int rr = 0; rr < 4; ++rr)
                    m = fmaxf(m, acc3[mt][nt][rr]);
            m = fmaxf(m, __shfl_xor(m, 16, 64));
            m = fmaxf(m, __shfl_xor(m, 32, 64));
            pool[nt] = m;
        }
        if (g == 0) {
            #pragma unroll
            for (int nt = 0; nt < 4; ++nt)
                atomicMax(&featsG[p * 256 + (4 * ntg + nt) * 16 + rc], __float_as_int(pool[nt]));
        }
    }
}

// One wave per proposal: 5 dot products of length 256.
__global__ __launch_bounds__(256) void heads_kernel(
    const int* __restrict__ featsG,
    const float* __restrict__ Wc, const float* __restrict__ bc,
    const float* __restrict__ Wr, const float* __restrict__ br,
    float* __restrict__ out, int P)
{
    const int tid  = threadIdx.x;
    const int lane = tid & 63;
    const int p    = blockIdx.x * 4 + (tid >> 6);
    if (p >= P) return;

    const int4 vi = *(const int4*)&featsG[p * 256 + lane * 4];
    float v[4] = {__int_as_float(vi.x), __int_as_float(vi.y),
                  __int_as_float(vi.z), __int_as_float(vi.w)};

    const float4 wc = *(const float4*)&Wc[lane * 4];
    float c  = v[0] * wc.x + v[1] * wc.y + v[2] * wc.z + v[3] * wc.w;
    float r0 = 0.f, r1 = 0.f, r2 = 0.f, r3 = 0.f;
    #pragma unroll
    for (int i = 0; i < 4; ++i) {
        const float4 wr = *(const float4*)&Wr[(lane * 4 + i) * 4];
        r0 = fmaf(v[i], wr.x, r0);
        r1 = fmaf(v[i], wr.y, r1);
        r2 = fmaf(v[i], wr.z, r2);
        r3 = fmaf(v[i], wr.w, r3);
    }
    #pragma unroll
    for (int off = 32; off > 0; off >>= 1) {
        c  += __shfl_xor(c,  off, 64);
        r0 += __shfl_xor(r0, off, 64);
        r1 += __shfl_xor(r1, off, 64);
        r2 += __shfl_xor(r2, off, 64);
        r3 += __shfl_xor(r3, off, 64);
    }
    if (lane == 0) {
        out[p]             = c  + bc[0];
        out[P + p * 4 + 0] = r0 + br[0];
        out[P + p * 4 + 1] = r1 + br[1];
        out[P + p * 4 + 2] = r2 + br[2];
        out[P + p * 4 + 3] = r3 + br[3];
    }
}

extern "C" void kernel_launch(void* const* d_in, const int* in_sizes, int n_in,
                              void* d_out, int out_size, void* d_ws, size_t ws_size,
                              hipStream_t stream)
{
    const float* points    = (const float*)d_in[0];
    const int*   lengths   = (const int*)  d_in[1];
    const float* proposals = (const float*)d_in[2];
    const float* W1 = (const float*)d_in[3];
    const float* b1 = (const float*)d_in[4];
    const float* W2 = (const float*)d_in[5];
    const float* b2 = (const float*)d_in[6];
    const float* W3 = (const float*)d_in[7];
    const float* b3 = (const float*)d_in[8];
    const float* Wc = (const float*)d_in[9];
    const float* bc = (const float*)d_in[10];
    const float* Wr = (const float*)d_in[11];
    const float* br = (const float*)d_in[12];
    float* out = (float*)d_out;

    const int P = in_sizes[1];              // 2048
    const int N = in_sizes[0] / (3 * P);    // 256
    const int S128 = (N + 127) / 128;       // 2 stripes of 128 points

    ushort* B2P    = (ushort*)d_ws;                 // 8192 bf16  (16 KB)
    ushort* B3P    = B2P + 8192;                    // 32768 bf16 (64 KB)
    int*    featsG = (int*)((char*)d_ws + 81920);   // P*256 ints (2 MB)

    hipMemsetAsync(featsG, 0, (size_t)P * 256 * sizeof(int), stream);
    pack_weights<<<dim3(128), dim3(256), 0, stream>>>(W2, W3, B2P, B3P);
    refine_stripe128<<<dim3(P * S128), dim3(512), 0, stream>>>(
        points, lengths, proposals, W1, b1, b2, b3, B2P, B3P, featsG, P, N);
    heads_kernel<<<dim3((P + 3) / 4), dim3(256), 0, stream>>>(
        featsG, Wc, bc, Wr, br, out, P);
}